// Round 8
// baseline (541.735 us; speedup 1.0000x reference)
//
#include <hip/hip_runtime.h>

// LSTM autoencoder: 4 layers 64->64, B=512, T=256 — fused, MFMA N fully used.
//
// 32 blocks x 512 threads. Block = 16 batch elements x all 4 layers.
// Wave w = (layer L = w>>1, unit-half mh = w&1); wave owns all 4 gates of
// units [mh*32, mh*32+32) => 8 M-tiles (g=0..3, j=0..1), MFMA cols = the 16
// batch elements (N fully used; round 6/7 used 2 of 16).
// Per tick (one barrier): read h/v fragments from LDS (f16, mod-3 rotated
// buffers) -> 32 MFMA -> epilogue IN REGISTERS (thread (q,n) holds all 4
// gates of its 8 units for element n straight from the C-fragments; cst[8]
// lives in VGPRs) -> pack h (f16x4) -> LDS write. No gate matrix round-trip.
// L0 input: x prefetched to registers one tick ahead (raw f32), converted
// to f16 fragments at use. L3 writes out as float4.
//
// Hb layout per (parity, L): [el n][unit-group g4] with 160 B per-n stride
// (16B aligned; reads land 8 dwords/bank — conflict-free). Unit-group g4 =
// u/4; writer (q,n) packs units mh*32+j*16+q*4+{0..3} = group mh*8+j*4+q.

typedef _Float16 f16x8 __attribute__((ext_vector_type(8)));
typedef float    f32x4 __attribute__((ext_vector_type(4)));

#define TSEQ   256
#define NEL    16
#define HSTR_N 160
#define HSTR_L (NEL * HSTR_N)   // 2560 B per layer
#define HSTR_P (4 * HSTR_L)     // 10240 B per parity
#define HB_TOT (3 * HSTR_P)     // 30720 B

__device__ __forceinline__ float fast_rcp(float x) { return __builtin_amdgcn_rcpf(x); }
__device__ __forceinline__ float sigm(float x) { return fast_rcp(1.0f + __expf(-x)); }
__device__ __forceinline__ float tanh_fast(float x) {
    return 2.0f * fast_rcp(1.0f + __expf(-2.0f * x)) - 1.0f;
}
__device__ __forceinline__ f16x8 cvt8(float4 a, float4 b) {
    f16x8 f;
    f[0] = (_Float16)a.x; f[1] = (_Float16)a.y; f[2] = (_Float16)a.z; f[3] = (_Float16)a.w;
    f[4] = (_Float16)b.x; f[5] = (_Float16)b.y; f[6] = (_Float16)b.z; f[7] = (_Float16)b.w;
    return f;
}
__device__ __forceinline__ int pkh(float a, float b) {
    unsigned lo = (unsigned)__builtin_bit_cast(unsigned short, (_Float16)a);
    unsigned hi = (unsigned)__builtin_bit_cast(unsigned short, (_Float16)b);
    return (int)(lo | (hi << 16));
}

__global__ __launch_bounds__(512, 2)
void lstm_fused4(const float* __restrict__ x,     // [512, 256, 64]
                 float* __restrict__ out,         // [512, 256, 64]
                 const float* __restrict__ Wih0, const float* __restrict__ Whh0,
                 const float* __restrict__ bi0,  const float* __restrict__ bh0,
                 const float* __restrict__ Wih1, const float* __restrict__ Whh1,
                 const float* __restrict__ bi1,  const float* __restrict__ bh1,
                 const float* __restrict__ Wih2, const float* __restrict__ Whh2,
                 const float* __restrict__ bi2,  const float* __restrict__ bh2,
                 const float* __restrict__ Wih3, const float* __restrict__ Whh3,
                 const float* __restrict__ bi3,  const float* __restrict__ bh3)
{
    __shared__ char Hb[HB_TOT];     // 30 KB: h state, 3 rotating parities

    const int tid  = threadIdx.x;
    const int wave = tid >> 6;
    const int lane = tid & 63;
    const int L    = wave >> 1;     // layer 0..3
    const int mh   = wave & 1;      // unit-half: units [mh*32, mh*32+32)
    const int q    = lane >> 4;     // quad
    const int n    = lane & 15;     // MFMA col = batch element in block
    const int b0   = blockIdx.x * NEL;

    const float* Wih = (L == 0) ? Wih0 : (L == 1) ? Wih1 : (L == 2) ? Wih2 : Wih3;
    const float* Whh = (L == 0) ? Whh0 : (L == 1) ? Whh1 : (L == 2) ? Whh2 : Whh3;
    const float* bi  = (L == 0) ? bi0  : (L == 1) ? bi1  : (L == 2) ? bi2  : bi3;
    const float* bh  = (L == 0) ? bh0  : (L == 1) ? bh1  : (L == 2) ? bh2  : bh3;

    // ---- persistent A-fragments: tile (g,j) rows g*64+mh*32+j*16+[0,16) ----
    // A layout: A[m=lane&15][k=q*8+jj]; chunks c: v-half cols c*32.., h same.
    f16x8 Aih[4][2][2], Ahh[4][2][2];
    f32x4 Cb[4][2];                 // bias C-init, C layout row=...q*4+r
#pragma unroll
    for (int g = 0; g < 4; ++g) {
#pragma unroll
        for (int j = 0; j < 2; ++j) {
            const int row = g * 64 + mh * 32 + j * 16 + n;
#pragma unroll
            for (int c = 0; c < 2; ++c) {
                const float* pi = Wih + row * 64 + c * 32 + q * 8;
                const float* ph = Whh + row * 64 + c * 32 + q * 8;
                f16x8 fi, fh;
#pragma unroll
                for (int k = 0; k < 8; ++k) { fi[k] = (_Float16)pi[k]; fh[k] = (_Float16)ph[k]; }
                Aih[g][j][c] = fi;
                Ahh[g][j][c] = fh;
            }
            f32x4 cb;
#pragma unroll
            for (int r = 0; r < 4; ++r) {
                const int br = g * 64 + mh * 32 + j * 16 + q * 4 + r;
                cb[r] = bi[br] + bh[br];
            }
            Cb[g][j] = cb;
        }
    }

    // ---- zero all three h buffers ----
    for (int i = tid; i < HB_TOT / 4; i += 512) ((int*)Hb)[i] = 0;

    // ---- L0 x prefetch: raw f32 regs one tick ahead ----
    const float* xbase = x + ((size_t)(b0 + n) * TSEQ) * 64 + q * 8;
    float4 R0, R1, R2, R3;
    if (L == 0) {
        const float* p = xbase;                     // x(0)
        R0 = *(const float4*)(p);      R1 = *(const float4*)(p + 4);
        R2 = *(const float4*)(p + 32); R3 = *(const float4*)(p + 36);
    }

    float cst[8];
#pragma unroll
    for (int i = 0; i < 8; ++i) cst[i] = 0.0f;

    float* outp = out + ((size_t)(b0 + n) * TSEQ) * 64 + mh * 32 + q * 4;  // L==3

    int pw = 0, pr = 2;   // write parity tau%3, read parity (tau-1)%3

    __syncthreads();

    for (int tau = 0; tau < TSEQ + 3; ++tau) {
        const int  t   = tau - L;
        const bool act = (unsigned)t < TSEQ;   // wave-uniform

        if (act) {
            // ---- input fragments ----
            f16x8 vf0, vf1;
            if (L == 0) {
                vf0 = cvt8(R0, R1);            // x(t), loaded last tick
                vf1 = cvt8(R2, R3);
                if (t + 1 < TSEQ) {            // prefetch x(t+1)
                    const float* p = xbase + (t + 1) * 64;
                    R0 = *(const float4*)(p);      R1 = *(const float4*)(p + 4);
                    R2 = *(const float4*)(p + 32); R3 = *(const float4*)(p + 36);
                }
            } else {
                const char* vp = Hb + pr * HSTR_P + (L - 1) * HSTR_L + n * HSTR_N + q * 16;
                vf0 = *(const f16x8*)(vp);
                vf1 = *(const f16x8*)(vp + 64);
            }
            const char* hp = Hb + pr * HSTR_P + L * HSTR_L + n * HSTR_N + q * 16;
            f16x8 hf0 = *(const f16x8*)(hp);
            f16x8 hf1 = *(const f16x8*)(hp + 64);

            char* wbase = Hb + pw * HSTR_P + L * HSTR_L + n * HSTR_N;

#pragma unroll
            for (int j = 0; j < 2; ++j) {
                // ---- 16 MFMA: 4 gate-tiles x 4 K-chunks ----
                f32x4 C[4];
#pragma unroll
                for (int g = 0; g < 4; ++g) {
                    f32x4 c = Cb[g][j];
                    c = __builtin_amdgcn_mfma_f32_16x16x32_f16(Ahh[g][j][0], hf0, c, 0, 0, 0);
                    c = __builtin_amdgcn_mfma_f32_16x16x32_f16(Ahh[g][j][1], hf1, c, 0, 0, 0);
                    c = __builtin_amdgcn_mfma_f32_16x16x32_f16(Aih[g][j][0], vf0, c, 0, 0, 0);
                    C[g] = __builtin_amdgcn_mfma_f32_16x16x32_f16(Aih[g][j][1], vf1, c, 0, 0, 0);
                }
                // ---- epilogue in registers: 4 units (el=n, u=mh*32+j*16+q*4+r) ----
                float hv[4];
#pragma unroll
                for (int r = 0; r < 4; ++r) {
                    float gi = sigm(C[0][r]);
                    float gf = sigm(C[1][r]);
                    float gg = tanh_fast(C[2][r]);
                    float go = sigm(C[3][r]);
                    float cs = gf * cst[j * 4 + r] + gi * gg;
                    cst[j * 4 + r] = cs;
                    hv[r] = go * tanh_fast(cs);
                }
                // pack 4 f16 and write h group
                int2 hw; hw.x = pkh(hv[0], hv[1]); hw.y = pkh(hv[2], hv[3]);
                *(int2*)(wbase + (mh * 8 + j * 4 + q) * 8) = hw;

                if (L == 3) {
                    float4 o4; o4.x = hv[0]; o4.y = hv[1]; o4.z = hv[2]; o4.w = hv[3];
                    *(float4*)(outp + t * 64 + j * 16) = o4;
                }
            }
        }
        __syncthreads();
        pw = (pw == 2) ? 0 : pw + 1;
        pr = (pr == 2) ? 0 : pr + 1;
    }
}

extern "C" void kernel_launch(void* const* d_in, const int* in_sizes, int n_in,
                              void* d_out, int out_size, void* d_ws, size_t ws_size,
                              hipStream_t stream) {
    const float* x = (const float*)d_in[0];
    float* out = (float*)d_out;

    lstm_fused4<<<32, 512, 0, stream>>>(
        x, out,
        (const float*)d_in[1],  (const float*)d_in[2],
        (const float*)d_in[3],  (const float*)d_in[4],
        (const float*)d_in[5],  (const float*)d_in[6],
        (const float*)d_in[7],  (const float*)d_in[8],
        (const float*)d_in[9],  (const float*)d_in[10],
        (const float*)d_in[11], (const float*)d_in[12],
        (const float*)d_in[13], (const float*)d_in[14],
        (const float*)d_in[15], (const float*)d_in[16]);
}

// Round 9
// 422.527 us; speedup vs baseline: 1.2821x; 1.2821x over previous
//
#include <hip/hip_runtime.h>

// LSTM autoencoder: 4 layers 64->64, B=512, T=256 — fused, single barrier/tick.
//
// 256 blocks x 512 threads (1 block/CU). Block = 2 batch elements x 4 layers.
// Wave w = (layer L = w>>1, unit-half mh = w&1) owns all 4 gates of units
// [mh*32, mh*32+32) via gate-split M-tiles (g=0..3, j=0..1).
// Per tick tau (layer L at t = tau-L):
//   1. read h (and v = h_{L-1} | x) fragments from LDS parity (tau+1)&1
//   2. 32 MFMA (16x16x32 f16), C cols 0..1 = the 2 batch elements
//   3. lanes n<2 write 8 gate-assembled float4 to a PER-WAVE LDS scratch;
//      same-wave ds_read (lgkmcnt-ordered, NO barrier) gives each of the 64
//      lanes its one (unit,el): epilogue 1 unit/lane, cst in 1 VGPR
//   4. h -> Hb[tau&1] (f16); L3 stores out; ONE __syncthreads()
// L0's x is prefetched one tick ahead into statically-named f32 regs
// (round-3 lesson: dynamic-index reg arrays spill to scratch).

typedef _Float16 f16x8 __attribute__((ext_vector_type(8)));
typedef float    f32x4 __attribute__((ext_vector_type(4)));

#define TSEQ 256

__device__ __forceinline__ float fast_rcp(float x) { return __builtin_amdgcn_rcpf(x); }
__device__ __forceinline__ float sigm(float x) { return fast_rcp(1.0f + __expf(-x)); }
__device__ __forceinline__ float tanh_fast(float x) {
    return 2.0f * fast_rcp(1.0f + __expf(-2.0f * x)) - 1.0f;
}
__device__ __forceinline__ f16x8 cvt8(float4 a, float4 b) {
    f16x8 f;
    f[0] = (_Float16)a.x; f[1] = (_Float16)a.y; f[2] = (_Float16)a.z; f[3] = (_Float16)a.w;
    f[4] = (_Float16)b.x; f[5] = (_Float16)b.y; f[6] = (_Float16)b.z; f[7] = (_Float16)b.w;
    return f;
}

__global__ __launch_bounds__(512, 2)
void lstm_fused5(const float* __restrict__ x,     // [512, 256, 64]
                 float* __restrict__ out,         // [512, 256, 64]
                 const float* __restrict__ Wih0, const float* __restrict__ Whh0,
                 const float* __restrict__ bi0,  const float* __restrict__ bh0,
                 const float* __restrict__ Wih1, const float* __restrict__ Whh1,
                 const float* __restrict__ bi1,  const float* __restrict__ bh1,
                 const float* __restrict__ Wih2, const float* __restrict__ Whh2,
                 const float* __restrict__ bi2,  const float* __restrict__ bh2,
                 const float* __restrict__ Wih3, const float* __restrict__ Whh3,
                 const float* __restrict__ bi3,  const float* __restrict__ bh3)
{
    __shared__ float4   Gs[8 * 64];          // 8 KB: per-wave gate scratch
    __shared__ _Float16 Hb[2][4][2][64];     // 2 KB: parity, layer, el, unit

    const int tid  = threadIdx.x;
    const int wave = tid >> 6;
    const int lane = tid & 63;
    const int L    = wave >> 1;     // layer 0..3
    const int mh   = wave & 1;      // unit-half: units [mh*32, mh*32+32)
    const int q    = lane >> 4;     // quad
    const int n    = lane & 15;     // MFMA col; valid batch cols are n<2
    const int b0   = blockIdx.x * 2;

    const float* Wih = (L == 0) ? Wih0 : (L == 1) ? Wih1 : (L == 2) ? Wih2 : Wih3;
    const float* Whh = (L == 0) ? Whh0 : (L == 1) ? Whh1 : (L == 2) ? Whh2 : Whh3;
    const float* bi  = (L == 0) ? bi0  : (L == 1) ? bi1  : (L == 2) ? bi2  : bi3;
    const float* bh  = (L == 0) ? bh0  : (L == 1) ? bh1  : (L == 2) ? bh2  : bh3;

    // ---- persistent A-fragments: tile (g,j) = rows g*64+mh*32+j*16+[0,16) ----
    // A layout: A[m=lane&15][k=q*8+kk]
    f16x8 Aih[4][2][2], Ahh[4][2][2];
#pragma unroll
    for (int g = 0; g < 4; ++g) {
#pragma unroll
        for (int j = 0; j < 2; ++j) {
            const int row = g * 64 + mh * 32 + j * 16 + n;
#pragma unroll
            for (int c = 0; c < 2; ++c) {
                const float* pi = Wih + row * 64 + c * 32 + q * 8;
                const float* ph = Whh + row * 64 + c * 32 + q * 8;
                f16x8 fi, fh;
#pragma unroll
                for (int k = 0; k < 8; ++k) { fi[k] = (_Float16)pi[k]; fh[k] = (_Float16)ph[k]; }
                Aih[g][j][c] = fi;
                Ahh[g][j][c] = fh;
            }
        }
    }

    // ---- epilogue identity: this lane owns (el = lane>>5, unit = mh*32+(lane&31)) ----
    const int eu = lane & 31;              // unit within half
    const int el = lane >> 5;
    const int unit = mh * 32 + eu;
    float4 be;
    be.x = bi[unit]       + bh[unit];
    be.y = bi[64 + unit]  + bh[64 + unit];
    be.z = bi[128 + unit] + bh[128 + unit];
    be.w = bi[192 + unit] + bh[192 + unit];
    float cst = 0.0f;
    float* outp = out + ((size_t)(b0 + el) * TSEQ) * 64 + unit;   // L==3 only

    // ---- zero h state (both parities): 2048 B = 512 ints ----
    ((int*)Hb)[tid] = 0;

    // ---- L0 x prefetch: raw f32 one tick ahead (lanes n<2 only; rest zero) ----
    const float* xbase = x + ((size_t)(b0 + (n & 1)) * TSEQ) * 64 + q * 8;
    float4 R0, R1, R2, R3;
    R0 = R1 = R2 = R3 = make_float4(0.f, 0.f, 0.f, 0.f);
    if (L == 0 && n < 2) {
        R0 = *(const float4*)(xbase);      R1 = *(const float4*)(xbase + 4);
        R2 = *(const float4*)(xbase + 32); R3 = *(const float4*)(xbase + 36);
    }

    __syncthreads();

    for (int tau = 0; tau < TSEQ + 3; ++tau) {
        const int  t   = tau - L;
        const bool act = (unsigned)t < TSEQ;   // wave-uniform
        const int  pr  = (tau + 1) & 1;
        const int  pw  = tau & 1;

        if (act) {
            // ---- input fragments ----
            f16x8 vf0, vf1;
            if (L == 0) {
                vf0 = cvt8(R0, R1);            // x(t)
                vf1 = cvt8(R2, R3);
                if (t + 1 < TSEQ && n < 2) {   // prefetch x(t+1)
                    const float* p = xbase + (t + 1) * 64;
                    R0 = *(const float4*)(p);      R1 = *(const float4*)(p + 4);
                    R2 = *(const float4*)(p + 32); R3 = *(const float4*)(p + 36);
                }
            } else {
                const _Float16* vp = &Hb[pr][L - 1][n & 1][0];
                vf0 = *(const f16x8*)(vp + q * 8);
                vf1 = *(const f16x8*)(vp + 32 + q * 8);
            }
            const _Float16* hp = &Hb[pr][L][n & 1][0];
            f16x8 hf0 = *(const f16x8*)(hp + q * 8);
            f16x8 hf1 = *(const f16x8*)(hp + 32 + q * 8);

            const f32x4 z4 = {0.f, 0.f, 0.f, 0.f};

            // ---- 32 MFMA + same-wave gate scatter (8 lanes write) ----
#pragma unroll
            for (int j = 0; j < 2; ++j) {
                f32x4 C[4];
#pragma unroll
                for (int g = 0; g < 4; ++g) {
                    f32x4 c;
                    c = __builtin_amdgcn_mfma_f32_16x16x32_f16(Ahh[g][j][0], hf0, z4, 0, 0, 0);
                    c = __builtin_amdgcn_mfma_f32_16x16x32_f16(Ahh[g][j][1], hf1, c,  0, 0, 0);
                    c = __builtin_amdgcn_mfma_f32_16x16x32_f16(Aih[g][j][0], vf0, c,  0, 0, 0);
                    C[g] = __builtin_amdgcn_mfma_f32_16x16x32_f16(Aih[g][j][1], vf1, c, 0, 0, 0);
                }
                if (n < 2) {
#pragma unroll
                    for (int r = 0; r < 4; ++r) {
                        float4 st;
                        st.x = C[0][r]; st.y = C[1][r]; st.z = C[2][r]; st.w = C[3][r];
                        // (unit-within-wave = j*16+q*4+r, el = n) -> linear slot
                        Gs[wave * 64 + n * 32 + j * 16 + q * 4 + r] = st;
                    }
                }
            }

            // ---- same-wave redistribute: 1 (unit,el) per lane, no barrier ----
            float4 gv = Gs[wave * 64 + lane];   // el=lane>>5, u'=lane&31

            float gi = sigm(gv.x + be.x);
            float gf = sigm(gv.y + be.y);
            float gg = tanh_fast(gv.z + be.z);
            float go = sigm(gv.w + be.w);
            cst = gf * cst + gi * gg;
            float h = go * tanh_fast(cst);

            if (L == 3) outp[t * 64] = h;
            Hb[pw][L][el][unit] = (_Float16)h;
        }
        __syncthreads();
    }
}

extern "C" void kernel_launch(void* const* d_in, const int* in_sizes, int n_in,
                              void* d_out, int out_size, void* d_ws, size_t ws_size,
                              hipStream_t stream) {
    const float* x = (const float*)d_in[0];
    float* out = (float*)d_out;

    lstm_fused5<<<256, 512, 0, stream>>>(
        x, out,
        (const float*)d_in[1],  (const float*)d_in[2],
        (const float*)d_in[3],  (const float*)d_in[4],
        (const float*)d_in[5],  (const float*)d_in[6],
        (const float*)d_in[7],  (const float*)d_in[8],
        (const float*)d_in[9],  (const float*)d_in[10],
        (const float*)d_in[11], (const float*)d_in[12],
        (const float*)d_in[13], (const float*)d_in[14],
        (const float*)d_in[15], (const float*)d_in[16]);
}